// Round 1
// baseline (171.059 us; speedup 1.0000x reference)
//
#include <hip/hip_runtime.h>

#define H_ 8
#define D_ 32
#define B_ 32
#define N_ 4096
#define C_ 256
#define EPS_ 1e-5f

// ---------------------------------------------------------------------------
// Kernel 1: per (b,h) accumulate S = U^T U (32x32) and t = column-sums of U,
// where U = rowwise-LayerNorm'd (unweighted) x-head slice.
// Grid: B*H*4 blocks (4 row-chunks of 1024 rows each), 256 threads.
// ---------------------------------------------------------------------------
__global__ __launch_bounds__(256, 4)
void k1_skv(const float* __restrict__ x, float* __restrict__ Sws, float* __restrict__ Tws)
{
    __shared__ float4 ubuf[256 * 8];   // 32 KB: [row][slot], slot = c ^ (row&7)

    const int tid   = threadIdx.x;
    const int bh    = blockIdx.x >> 2;
    const int chunk = blockIdx.x & 3;
    const int b     = bh >> 3;
    const int h     = bh & 7;
    const int lane  = tid & 63;
    const int wave  = tid >> 6;
    const int dg    = lane >> 3;       // 0..7  (d-group of 4)
    const int eg    = lane & 7;        // 0..7  (e-group of 4)

    float acc[4][4];
    #pragma unroll
    for (int i = 0; i < 4; ++i)
        #pragma unroll
        for (int j = 0; j < 4; ++j) acc[i][j] = 0.f;

    float4 tacc[8];
    #pragma unroll
    for (int c = 0; c < 8; ++c) tacc[c] = make_float4(0.f, 0.f, 0.f, 0.f);

    for (int it = 0; it < 4; ++it) {
        const int row0 = chunk * 1024 + it * 256;

        // ---- stage-in: coalesced global -> swizzled LDS (256 rows x 32 floats)
        #pragma unroll
        for (int k = 0; k < 8; ++k) {
            const int g   = tid + k * 256;     // float4-chunk index, 0..2047
            const int row = g >> 3;            // 0..255
            const int c   = g & 7;             // chunk within row
            const float4 xv = *reinterpret_cast<const float4*>(
                x + ((size_t)b * N_ + row0 + row) * C_ + h * D_ + c * 4);
            ubuf[row * 8 + (c ^ (row & 7))] = xv;
        }
        __syncthreads();

        // ---- per-lane LayerNorm on own row (row == tid), fully lane-private
        {
            const int sw = tid & 7;
            float sum = 0.f, sq = 0.f;
            #pragma unroll
            for (int c = 0; c < 8; ++c) {
                const float4 a = ubuf[tid * 8 + (c ^ sw)];
                sum += a.x + a.y + a.z + a.w;
                sq  += a.x * a.x + a.y * a.y + a.z * a.z + a.w * a.w;
            }
            const float m   = sum * (1.f / 32.f);
            const float ss  = fmaxf(sq - sum * m, 0.f);          // sum of squared devs
            const float inv = 1.f / (sqrtf(ss * (1.f / 31.f)) + EPS_); // unbiased std + eps
            #pragma unroll
            for (int c = 0; c < 8; ++c) {
                const int slot = tid * 8 + (c ^ sw);
                const float4 a = ubuf[slot];
                float4 u;
                u.x = (a.x - m) * inv; u.y = (a.y - m) * inv;
                u.z = (a.z - m) * inv; u.w = (a.w - m) * inv;
                tacc[c].x += u.x; tacc[c].y += u.y; tacc[c].z += u.z; tacc[c].w += u.w;
                ubuf[slot] = u;
            }
        }
        __syncthreads();

        // ---- rank-256 update of S: each wave owns a full 32x32 copy, 64 rows
        const int r0 = wave * 64;
        #pragma unroll 4
        for (int rr = r0; rr < r0 + 64; ++rr) {
            const int s = rr & 7;
            const float4 a = ubuf[rr * 8 + (dg ^ s)];   // u[rr][4dg..4dg+3]
            const float4 v = ubuf[rr * 8 + (eg ^ s)];   // u[rr][4eg..4eg+3]
            acc[0][0] += a.x * v.x; acc[0][1] += a.x * v.y; acc[0][2] += a.x * v.z; acc[0][3] += a.x * v.w;
            acc[1][0] += a.y * v.x; acc[1][1] += a.y * v.y; acc[1][2] += a.y * v.z; acc[1][3] += a.y * v.w;
            acc[2][0] += a.z * v.x; acc[2][1] += a.z * v.y; acc[2][2] += a.z * v.z; acc[2][3] += a.z * v.w;
            acc[3][0] += a.w * v.x; acc[3][1] += a.w * v.y; acc[3][2] += a.w * v.z; acc[3][3] += a.w * v.w;
        }
        __syncthreads();
    }

    // ---- S partial -> global (atomic; ws pre-zeroed)
    float* Sb = Sws + (size_t)bh * (D_ * D_);
    #pragma unroll
    for (int i = 0; i < 4; ++i)
        #pragma unroll
        for (int j = 0; j < 4; ++j)
            atomicAdd(Sb + (dg * 4 + i) * D_ + (eg * 4 + j), acc[i][j]);

    // ---- t reduce: dump per-thread partials into (now free) ubuf, reduce cols
    #pragma unroll
    for (int c = 0; c < 8; ++c) ubuf[tid * 8 + c] = tacc[c];
    __syncthreads();
    if (tid < D_) {
        const float* uf = reinterpret_cast<const float*>(ubuf);
        float s = 0.f;
        #pragma unroll 8
        for (int i = 0; i < 256; ++i) s += uf[i * 32 + tid];
        atomicAdd(Tws + bh * D_ + tid, s);
    }
}

// ---------------------------------------------------------------------------
// Kernel 2: out[b,n,c] = x[b,n,c] + sum_d x[b,n,h*32+d] * kv[b,h][d][e]
// kv rebuilt from S,t with weights/biases folded in.
// Grid: B*64 blocks (64-row chunks), 256 threads; thread owns column c = tid.
// ---------------------------------------------------------------------------
__global__ __launch_bounds__(256, 4)
void k2_out(const float* __restrict__ x,
            const float* __restrict__ Sws, const float* __restrict__ Tws,
            const float* __restrict__ kw, const float* __restrict__ kb,
            const float* __restrict__ vw, const float* __restrict__ vb,
            float* __restrict__ out)
{
    __shared__ float xbuf[4 * C_];     // 4 rows staged, 4 KB

    const int tid   = threadIdx.x;
    const int b     = blockIdx.x >> 6;
    const int chunk = blockIdx.x & 63;
    const int h     = tid >> 5;
    const int e     = tid & 31;
    const int bh    = b * 8 + h;

    const float* S = Sws + (size_t)bh * (D_ * D_);
    const float* T = Tws + bh * D_;
    const float wve  = vw[h * D_ + e];
    const float bve  = vb[h * D_ + e];
    const float Te   = T[e];
    const float invN = 1.f / (float)N_;

    // kv column e for head h, in registers
    float kvc[32];
    #pragma unroll
    for (int d = 0; d < D_; ++d) {
        const float wkd = kw[h * D_ + d];
        const float bkd = kb[h * D_ + d];
        kvc[d] = invN * (wkd * (wve * S[d * D_ + e] + bve * T[d]) + bkd * wve * Te)
               + bkd * bve;
    }

    for (int it = 0; it < 16; ++it) {
        const int r0 = chunk * 64 + it * 4;
        const float* xrow = x + ((size_t)b * N_ + r0) * C_;
        const float4 xv = reinterpret_cast<const float4*>(xrow)[tid]; // 4 rows coalesced
        __syncthreads();                       // protect previous iter's reads
        reinterpret_cast<float4*>(xbuf)[tid] = xv;
        __syncthreads();

        float res[4];
        #pragma unroll
        for (int r = 0; r < 4; ++r) {
            const float4* xr4 = reinterpret_cast<const float4*>(xbuf + r * C_ + h * D_);
            float dot = 0.f;
            #pragma unroll
            for (int c = 0; c < 8; ++c) {
                const float4 a = xr4[c];
                dot += a.x * kvc[c * 4 + 0] + a.y * kvc[c * 4 + 1]
                     + a.z * kvc[c * 4 + 2] + a.w * kvc[c * 4 + 3];
            }
            res[r] = dot + xbuf[r * C_ + tid];  // + residual x
        }
        float* orow = out + ((size_t)b * N_ + r0) * C_;
        #pragma unroll
        for (int r = 0; r < 4; ++r) orow[r * C_ + tid] = res[r];
    }
}

extern "C" void kernel_launch(void* const* d_in, const int* in_sizes, int n_in,
                              void* d_out, int out_size, void* d_ws, size_t ws_size,
                              hipStream_t stream)
{
    const float* x  = (const float*)d_in[0];
    const float* kw = (const float*)d_in[1];
    const float* kb = (const float*)d_in[2];
    const float* vw = (const float*)d_in[3];
    const float* vb = (const float*)d_in[4];
    float* outp = (float*)d_out;

    float* Sws = (float*)d_ws;                                  // B*H*32*32 floats (1 MB)
    float* Tws = Sws + (size_t)B_ * H_ * D_ * D_;               // B*H*32 floats (32 KB)
    const size_t zero_bytes =
        ((size_t)B_ * H_ * D_ * D_ + (size_t)B_ * H_ * D_) * sizeof(float);
    hipMemsetAsync(d_ws, 0, zero_bytes, stream);

    k1_skv<<<dim3(B_ * H_ * 4), dim3(256), 0, stream>>>(x, Sws, Tws);
    k2_out<<<dim3(B_ * 64), dim3(256), 0, stream>>>(x, Sws, Tws, kw, kb, vw, vb, outp);
}

// Round 2
// 100.516 us; speedup vs baseline: 1.7018x; 1.7018x over previous
//
#include <hip/hip_runtime.h>

#define H_ 8
#define D_ 32
#define B_ 32
#define N_ 4096
#define C_ 256
#define EPS_ 1e-5f

typedef __attribute__((ext_vector_type(8))) short bf16x8;
typedef __attribute__((ext_vector_type(4))) float f32x4;

__device__ __forceinline__ short f2bf(float f) {
    unsigned u = __builtin_bit_cast(unsigned, f);
    unsigned r = (u + 0x7FFFu + ((u >> 16) & 1u)) >> 16;
    return (short)r;
}

// physical short-index of (row, col) in ubuf: 80 B row stride + 32 B shift per
// 8-row group -> fragment reads conflict-free, writes at the 8-way floor.
__device__ __forceinline__ int uidx(int r, int c) {
    return r * 40 + ((r >> 3) & 3) * 16 + c;
}

// ---------------------------------------------------------------------------
// Kernel 1: per (b,h) accumulate S = U^T U (32x32) and t = colsum(U) via MFMA.
// U = rowwise-LN'd x-head slice, bf16. Grid: B*H*4 blocks, 256 threads.
// Each wave owns rows [wave*64, wave*64+64) of each 256-row iter -> LDS is
// wave-private; barriers kept for write->read ordering only.
// ---------------------------------------------------------------------------
__global__ __launch_bounds__(256, 4)
void k1_skv(const float* __restrict__ x, float* __restrict__ Sws, float* __restrict__ Tws)
{
    __shared__ short ubuf[256 * 40 + 64];

    const int tid  = threadIdx.x;
    const int bh   = blockIdx.x >> 2;
    const int q4   = blockIdx.x & 3;
    const int b    = bh >> 3;
    const int h    = bh & 7;
    const int lane = tid & 63;
    const int wave = tid >> 6;
    const int g    = lane >> 4;      // 0..3 : k-group
    const int cL   = lane & 15;      // 0..15: column within 16-block

    f32x4 acc[2][2] = {};            // S quadrants [ca][cb]
    f32x4 tq[2] = {};                // column sums via ones-MFMA

    bf16x8 ones;
    #pragma unroll
    for (int j = 0; j < 8; ++j) ones[j] = (short)0x3F80;   // bf16 1.0

    const float* xbase = x + ((size_t)b * N_ + q4 * 1024) * C_ + h * D_;

    // preload iter 0 (one full row per thread; 8 x 16B within one 128B line)
    float4 xr[8];
    {
        const float4* p = reinterpret_cast<const float4*>(xbase + (size_t)tid * C_);
        #pragma unroll
        for (int c = 0; c < 8; ++c) xr[c] = p[c];
    }

    for (int it = 0; it < 4; ++it) {
        // ---- LN stats, fully lane-private
        float sum = 0.f, sq = 0.f;
        #pragma unroll
        for (int c = 0; c < 8; ++c) {
            const float4 a = xr[c];
            sum += a.x + a.y + a.z + a.w;
            sq = fmaf(a.x, a.x, fmaf(a.y, a.y, fmaf(a.z, a.z, fmaf(a.w, a.w, sq))));
        }
        const float m   = sum * (1.f / 32.f);
        const float ss  = fmaxf(sq - sum * m, 0.f);
        const float inv = 1.f / (sqrtf(ss * (1.f / 31.f)) + EPS_);

        // ---- u -> bf16, packed into 4 x short8
        bf16x8 wv[4];
        #pragma unroll
        for (int q = 0; q < 4; ++q) {
            const float4 a0 = xr[q * 2 + 0];
            const float4 a1 = xr[q * 2 + 1];
            wv[q][0] = f2bf((a0.x - m) * inv); wv[q][1] = f2bf((a0.y - m) * inv);
            wv[q][2] = f2bf((a0.z - m) * inv); wv[q][3] = f2bf((a0.w - m) * inv);
            wv[q][4] = f2bf((a1.x - m) * inv); wv[q][5] = f2bf((a1.y - m) * inv);
            wv[q][6] = f2bf((a1.z - m) * inv); wv[q][7] = f2bf((a1.w - m) * inv);
        }

        __syncthreads();             // prev iter's fragment reads done
        {
            const int base = tid * 40 + ((tid >> 3) & 3) * 16;
            #pragma unroll
            for (int q = 0; q < 4; ++q)
                *reinterpret_cast<bf16x8*>(&ubuf[base + q * 8]) = wv[q];
        }
        __syncthreads();             // writes visible

        // ---- prefetch next iter's row (stays in flight under MFMA phase)
        if (it < 3) {
            const float4* p = reinterpret_cast<const float4*>(
                xbase + ((size_t)(it + 1) * 256 + tid) * C_);
            #pragma unroll
            for (int c = 0; c < 8; ++c) xr[c] = p[c];
        }

        // ---- fragment + MFMA phase: wave-private 64 rows, 2 K-steps of 32
        #pragma unroll
        for (int ks = 0; ks < 2; ++ks) {
            const int R0 = wave * 64 + ks * 32 + 8 * g;
            bf16x8 F0, F1;
            #pragma unroll
            for (int j = 0; j < 8; ++j) {
                const int base = uidx(R0 + j, cL);
                F0[j] = ubuf[base];
                F1[j] = ubuf[base + 16];
            }
            tq[0] = __builtin_amdgcn_mfma_f32_16x16x32_bf16(ones, F0, tq[0], 0, 0, 0);
            tq[1] = __builtin_amdgcn_mfma_f32_16x16x32_bf16(ones, F1, tq[1], 0, 0, 0);
            acc[0][0] = __builtin_amdgcn_mfma_f32_16x16x32_bf16(F0, F0, acc[0][0], 0, 0, 0);
            acc[0][1] = __builtin_amdgcn_mfma_f32_16x16x32_bf16(F0, F1, acc[0][1], 0, 0, 0);
            acc[1][0] = __builtin_amdgcn_mfma_f32_16x16x32_bf16(F1, F0, acc[1][0], 0, 0, 0);
            acc[1][1] = __builtin_amdgcn_mfma_f32_16x16x32_bf16(F1, F1, acc[1][1], 0, 0, 0);
        }
    }

    // ---- epilogue: C/D layout col=lane&15, row=(lane>>4)*4+reg  [m89]
    float* Sb = Sws + (size_t)bh * (D_ * D_);
    const int mr = g * 4;
    #pragma unroll
    for (int ca = 0; ca < 2; ++ca)
        #pragma unroll
        for (int cb = 0; cb < 2; ++cb)
            #pragma unroll
            for (int r = 0; r < 4; ++r)
                atomicAdd(Sb + (ca * 16 + mr + r) * D_ + cb * 16 + cL, acc[ca][cb][r]);

    if (lane < 16) {                 // every lane/reg holds t[col]; use g==0,reg0
        atomicAdd(Tws + bh * D_ + cL,      tq[0][0]);
        atomicAdd(Tws + bh * D_ + 16 + cL, tq[1][0]);
    }
}

// ---------------------------------------------------------------------------
// Kernel 2: out[b,n,c] = x[b,n,c] + sum_d x[b,n,h*32+d] * kv[b,h][d][e]
// kv rebuilt from S,t with weights/biases folded in. (unchanged from R1)
// ---------------------------------------------------------------------------
__global__ __launch_bounds__(256, 4)
void k2_out(const float* __restrict__ x,
            const float* __restrict__ Sws, const float* __restrict__ Tws,
            const float* __restrict__ kw, const float* __restrict__ kb,
            const float* __restrict__ vw, const float* __restrict__ vb,
            float* __restrict__ out)
{
    __shared__ float xbuf[4 * C_];

    const int tid   = threadIdx.x;
    const int b     = blockIdx.x >> 6;
    const int chunk = blockIdx.x & 63;
    const int h     = tid >> 5;
    const int e     = tid & 31;
    const int bh    = b * 8 + h;

    const float* S = Sws + (size_t)bh * (D_ * D_);
    const float* T = Tws + bh * D_;
    const float wve  = vw[h * D_ + e];
    const float bve  = vb[h * D_ + e];
    const float Te   = T[e];
    const float invN = 1.f / (float)N_;

    float kvc[32];
    #pragma unroll
    for (int d = 0; d < D_; ++d) {
        const float wkd = kw[h * D_ + d];
        const float bkd = kb[h * D_ + d];
        kvc[d] = invN * (wkd * (wve * S[d * D_ + e] + bve * T[d]) + bkd * wve * Te)
               + bkd * bve;
    }

    for (int it = 0; it < 16; ++it) {
        const int r0 = chunk * 64 + it * 4;
        const float* xrow = x + ((size_t)b * N_ + r0) * C_;
        const float4 xv = reinterpret_cast<const float4*>(xrow)[tid];
        __syncthreads();
        reinterpret_cast<float4*>(xbuf)[tid] = xv;
        __syncthreads();

        float res[4];
        #pragma unroll
        for (int r = 0; r < 4; ++r) {
            const float4* xr4 = reinterpret_cast<const float4*>(xbuf + r * C_ + h * D_);
            float dot = 0.f;
            #pragma unroll
            for (int c = 0; c < 8; ++c) {
                const float4 a = xr4[c];
                dot += a.x * kvc[c * 4 + 0] + a.y * kvc[c * 4 + 1]
                     + a.z * kvc[c * 4 + 2] + a.w * kvc[c * 4 + 3];
            }
            res[r] = dot + xbuf[r * C_ + tid];
        }
        float* orow = out + ((size_t)b * N_ + r0) * C_;
        #pragma unroll
        for (int r = 0; r < 4; ++r) orow[r * C_ + tid] = res[r];
    }
}

extern "C" void kernel_launch(void* const* d_in, const int* in_sizes, int n_in,
                              void* d_out, int out_size, void* d_ws, size_t ws_size,
                              hipStream_t stream)
{
    const float* x  = (const float*)d_in[0];
    const float* kw = (const float*)d_in[1];
    const float* kb = (const float*)d_in[2];
    const float* vw = (const float*)d_in[3];
    const float* vb = (const float*)d_in[4];
    float* outp = (float*)d_out;

    float* Sws = (float*)d_ws;
    float* Tws = Sws + (size_t)B_ * H_ * D_ * D_;
    const size_t zero_bytes =
        ((size_t)B_ * H_ * D_ * D_ + (size_t)B_ * H_ * D_) * sizeof(float);
    hipMemsetAsync(d_ws, 0, zero_bytes, stream);

    k1_skv<<<dim3(B_ * H_ * 4), dim3(256), 0, stream>>>(x, Sws, Tws);
    k2_out<<<dim3(B_ * 64), dim3(256), 0, stream>>>(x, Sws, Tws, kw, kb, vw, vb, outp);
}